// Round 11
// baseline (261.849 us; speedup 1.0000x reference)
//
#include <hip/hip_runtime.h>
#include <hip/hip_cooperative_groups.h>
#include <stdint.h>

namespace cg = cooperative_groups;

#define DIM_IN  4096
#define DIM_OUT 4096
#define BATCH   64

typedef unsigned long long u64;
typedef uint32_t u32;

#define NBLK  512
#define NTHRD (NBLK * 256)   // 131072 threads
#define NUNIT 4194304        // 16.7M words / 4 (uint4) == 16.7MB bytes / 4 (u32)

// ---------------------------------------------------------------------------
// Input-format detection (first 8 u32 words):
//   int32 0/1 or float 0.0/1.0 -> "word" layout (4B/bool)
//   uint8 0/1                  -> "byte" layout (1B/bool)
// Rounds 3-10: FETCH ~33.4 MB pins word encoding. P(misclassify) ~ 2^-192.
// ---------------------------------------------------------------------------
__device__ __forceinline__ bool is_word_fmt(const u32* __restrict__ p) {
    bool words = true;
#pragma unroll
    for (int i = 0; i < 8; ++i) {
        u32 v = p[i];
        if (v > 1u && v != 0x3F800000u) words = false;
    }
    return words;
}

// ---------------------------------------------------------------------------
// ONE cooperative kernel, 512 blocks x 256 threads, 3 phases + grid.sync().
//
// P1 compress: pure linear grid-stride read of masks -> row-major bitmatrix
//   rp (67 MB -> 2 MB). Unit = uint4 (word mode) or u32 (byte mode) = 4
//   columns either way; unit index g: wave chunk = g>>6, ballot bit L = lane.
//   rp[chunk*4 + c] bit L = unit g = chunk*64+L, component c.
//   (Round-10 compress math, NTHR rescaled; verified absmax 0.)
//   Blocks 496..511 additionally pack x -> xp via wave ballot.
//
// P2 transpose: 64x64 bit tiles rp -> canonical mp[w][o]; wave does 2 tiles;
//   lane r holds row w*64+r's 4 words; 64 ballots; lane d keeps column word
//   d; coalesced u64 store. (Round-10 body, rep-looped; verified absmax 0.)
//
// P3 bnn: out[b][o] = (4096 - sum_w popc(xp[b][w]^mp[w][o])) > thr[o].
//   Block: o-block = bid&15 (256 cols), b0 = (bid>>4)*2 (2 rows/thread).
// ---------------------------------------------------------------------------
__global__ __launch_bounds__(256) void fused_kernel(
        const void* __restrict__ masks, const void* __restrict__ x,
        const int* __restrict__ thr, u64* __restrict__ rp,
        u64* __restrict__ mp, u64* __restrict__ xp, int* __restrict__ out) {
    cg::grid_group grid = cg::this_grid();
    const int bid  = blockIdx.x;
    const int tid  = threadIdx.x;
    const int lane = tid & 63;

    // ------------------------- P1: compress + xpack -------------------------
    {
        const bool words = is_word_fmt((const u32*)masks);
        const int T = bid * 256 + tid;                 // 0..131071
        if (words) {
            const uint4* src = (const uint4*)masks;    // 4M uint4
#pragma unroll
            for (int batch = 0; batch < 4; ++batch) {
                uint4 v[8];
#pragma unroll
                for (int r = 0; r < 8; ++r)
                    v[r] = src[(size_t)T + (size_t)(batch * 8 + r) * NTHRD];
#pragma unroll
                for (int r = 0; r < 8; ++r) {
                    const u64 b0 = __ballot(v[r].x != 0u);
                    const u64 b1 = __ballot(v[r].y != 0u);
                    const u64 b2 = __ballot(v[r].z != 0u);
                    const u64 b3 = __ballot(v[r].w != 0u);
                    const size_t chunk =
                        ((size_t)T + (size_t)(batch * 8 + r) * NTHRD) >> 6;
                    if (lane < 4) {
                        const u64 bb = lane == 0 ? b0 : lane == 1 ? b1
                                     : lane == 2 ? b2 : b3;
                        rp[chunk * 4 + lane] = bb;
                    }
                }
            }
        } else {
            const u32* src = (const u32*)masks;        // 4M u32 (byte mode)
#pragma unroll
            for (int batch = 0; batch < 4; ++batch) {
                u32 v[8];
#pragma unroll
                for (int r = 0; r < 8; ++r)
                    v[r] = src[(size_t)T + (size_t)(batch * 8 + r) * NTHRD];
#pragma unroll
                for (int r = 0; r < 8; ++r) {
                    const u64 b0 = __ballot((v[r] & 0x000000FFu) != 0u);
                    const u64 b1 = __ballot((v[r] & 0x0000FF00u) != 0u);
                    const u64 b2 = __ballot((v[r] & 0x00FF0000u) != 0u);
                    const u64 b3 = __ballot((v[r] & 0xFF000000u) != 0u);
                    const size_t chunk =
                        ((size_t)T + (size_t)(batch * 8 + r) * NTHRD) >> 6;
                    if (lane < 4) {
                        const u64 bb = lane == 0 ? b0 : lane == 1 ? b1
                                     : lane == 2 ? b2 : b3;
                        rp[chunk * 4 + lane] = bb;
                    }
                }
            }
        }

        if (bid >= NBLK - 16) {
            // ------------------- x pack (16 blocks, 64 waves) -------------------
            const bool xwords = is_word_fmt((const u32*)x);
            const int bxid = bid - (NBLK - 16);               // 0..15
            const int wave = bxid * 4 + (tid >> 6);           // 0..63
            const int base = wave * 64;                       // word index base
#pragma unroll 16
            for (int k = 0; k < 64; ++k) {
                const int idx = base + k;                     // 0..4095
                const size_t e = (size_t)idx * 64 + lane;     // element index
                bool pred;
                if (xwords) pred = ((const u32*)x)[e] != 0u;
                else        pred = ((const uint8_t*)x)[e] != 0u;
                const u64 m = __ballot(pred);
                if (lane == 0) xp[idx] = m;
            }
        }
    }

    __threadfence();
    grid.sync();

    // --------------------------- P2: transpose -----------------------------
    {
        const int wv = tid >> 6;                              // 0..3
#pragma unroll
        for (int rep = 0; rep < 2; ++rep) {
            const int wg   = (bid * 4 + wv) * 2 + rep;        // 0..4095
            const int w    = wg >> 6;                         // 0..63
            const int oseg = wg & 63;                         // 0..63
            const int r    = lane;
            const int o0   = oseg * 64;
            const int jbase = (o0 >> 8) * 4;
            const int Lbase = (o0 & 255) >> 2;                // 0,16,32,48

            const u64* rowp = rp + (size_t)(w * 64 + r) * 64 + jbase;
            const u64 rw0 = rowp[0];
            const u64 rw1 = rowp[1];
            const u64 rw2 = rowp[2];
            const u64 rw3 = rowp[3];

            u64 mine = 0;
#pragma unroll
            for (int d = 0; d < 64; ++d) {
                const u64 srcw = (d & 3) == 0 ? rw0 : (d & 3) == 1 ? rw1
                               : (d & 3) == 2 ? rw2 : rw3;
                const int sh = Lbase + (d >> 2);
                const u64 m = __ballot(((srcw >> sh) & 1ull) != 0ull);
                if (r == d) mine = m;
            }
            mp[(size_t)w * DIM_OUT + o0 + r] = mine;
        }
    }

    __threadfence();
    grid.sync();

    // ------------------------------ P3: bnn --------------------------------
    {
        const int o  = (bid & 15) * 256 + tid;                // 0..4095
        const int b0 = (bid >> 4) * 2;                        // 0,2,..,62

        const u64* __restrict__ x0 = xp + (size_t)(b0 + 0) * 64;
        const u64* __restrict__ x1 = xp + (size_t)(b0 + 1) * 64;

        int a0 = 0, a1 = 0;
#pragma unroll 16
        for (int w = 0; w < 64; ++w) {
            const u64 mw = mp[(size_t)w * DIM_OUT + o];
            a0 += __popcll(x0[w] ^ mw);
            a1 += __popcll(x1[w] ^ mw);
        }

        const int t = thr[o];
        out[(size_t)(b0 + 0) * DIM_OUT + o] = (DIM_IN - a0) > t ? 1 : 0;
        out[(size_t)(b0 + 1) * DIM_OUT + o] = (DIM_IN - a1) > t ? 1 : 0;
    }
}

// ---------------------------------------------------------------------------
extern "C" void kernel_launch(void* const* d_in, const int* in_sizes, int n_in,
                              void* d_out, int out_size, void* d_ws, size_t ws_size,
                              hipStream_t stream) {
    const void* masks_x = d_in[0];               // bool [64][4096]
    const void* masks   = d_in[1];               // bool [4096][4096]
    const int*  thr     = (const int*)d_in[2];   // int32 [4096]
    int* out = (int*)d_out;                      // [64][4096] int32 0/1

    u64* rp = (u64*)d_ws;                                        // 2 MiB
    u64* mp = (u64*)((char*)d_ws + (size_t)2 * 1024 * 1024);     // 2 MiB
    u64* xp = (u64*)((char*)d_ws + (size_t)4 * 1024 * 1024);     // 32 KiB

    void* args[] = {
        (void*)&masks,   // const void* masks
        (void*)&masks_x, // const void* x
        (void*)&thr,
        (void*)&rp,
        (void*)&mp,
        (void*)&xp,
        (void*)&out,
    };
    hipLaunchCooperativeKernel((const void*)fused_kernel,
                               dim3(NBLK), dim3(256), args, 0, stream);
}

// Round 12
// 106.409 us; speedup vs baseline: 2.4608x; 2.4608x over previous
//
#include <hip/hip_runtime.h>
#include <stdint.h>

#define DIM_IN  4096
#define DIM_OUT 4096
#define BATCH   64

typedef unsigned long long u64;
typedef uint32_t u32;

// ---------------------------------------------------------------------------
// Input-format detection (first 8 u32 words):
//   int32 0/1 or float 0.0/1.0 -> "word" layout (4B/bool)
//   uint8 0/1                  -> "byte" layout (1B/bool)
// Rounds 3-10: FETCH ~33.4 MB pins word encoding. P(misclassify) ~ 2^-192.
// ---------------------------------------------------------------------------
__device__ __forceinline__ bool is_word_fmt(const u32* __restrict__ p) {
    bool words = true;
#pragma unroll
    for (int i = 0; i < 8; ++i) {
        u32 v = p[i];
        if (v > 1u && v != 0x3F800000u) words = false;
    }
    return words;
}

// ---------------------------------------------------------------------------
// ONE plain dispatch, 256 blocks x 256 threads. Block owns 16 output columns
// o0 = bid*16. No global intermediates, no grid sync — each block produces
// everything it consumes (LDS only). Saves 1 dispatch overhead + 5 MB of
// mp/xp global round-trip vs the round-8 two-kernel pipeline.
//
// Bit-order convention (both sides identical => popc pairing correct):
//   bit l of group (g, cc) <-> row/element index i = g*256 + 4*l + cc.
//
// Phase B (masks -> mpl LDS, 8 KB): thread (c16 = tid&15, s = tid>>4) owns
//   column o0+c16, row-slice s*256..+255. 256 strided dword loads, 16-deep
//   staged; acc[cc] |= (v!=0) << (r>>2) with cc = r&3 (compile-time).
//   mpl[(g*4+cc)*16 + c16], g = s.
// Phase A (x -> xp LDS, 32 KB): linear uint4 + 4 ballots per iteration
//   (r10 compress math): word-block B = v*256+k covers x words B*256..+255;
//   ballot c bit l = word B*256+4l+c  ->  xp[B*4+c]. B = b*16+g.
// Phase C: thread (c16, bq = tid>>4): out[b][o0+c16] for b = bq*4..+3;
//   a += popc(xp[(b*16+g)*4+cc] ^ mpl[(g*4+cc)*16+c16]) over 64 (g,cc).
// ---------------------------------------------------------------------------
__global__ __launch_bounds__(256) void fused1_kernel(
        const void* __restrict__ masks, const void* __restrict__ x,
        const int* __restrict__ thr, int* __restrict__ out) {
    __shared__ u64 xp[64 * 64];    // [b*16+g][cc]  (32 KB)
    __shared__ u64 mpl[64 * 16];   // [(g*4+cc)][c16] (8 KB)

    const int tid  = threadIdx.x;
    const int lane = tid & 63;
    const int o0   = blockIdx.x * 16;

    // ------------------- Phase B: mask pack (long pole, start first) -------
    {
        const bool words = is_word_fmt((const u32*)masks);
        const int c16 = tid & 15;
        const int s   = tid >> 4;                       // 0..15
        u64 acc[4] = {0ull, 0ull, 0ull, 0ull};

        if (words) {
            const u32* base = (const u32*)masks
                            + (size_t)(s * 256) * DIM_OUT + o0 + c16;
#pragma unroll
            for (int rb = 0; rb < 16; ++rb) {
                u32 v[16];
#pragma unroll
                for (int rr = 0; rr < 16; ++rr)
                    v[rr] = base[(size_t)(rb * 16 + rr) * DIM_OUT];
#pragma unroll
                for (int rr = 0; rr < 16; ++rr) {
                    const int r = rb * 16 + rr;         // 0..255, compile-time
                    acc[r & 3] |= (u64)(v[rr] != 0u) << (r >> 2);
                }
            }
        } else {
            const uint8_t* base = (const uint8_t*)masks
                                + (size_t)(s * 256) * DIM_OUT + o0 + c16;
#pragma unroll
            for (int rb = 0; rb < 16; ++rb) {
                uint8_t v[16];
#pragma unroll
                for (int rr = 0; rr < 16; ++rr)
                    v[rr] = base[(size_t)(rb * 16 + rr) * DIM_OUT];
#pragma unroll
                for (int rr = 0; rr < 16; ++rr) {
                    const int r = rb * 16 + rr;
                    acc[r & 3] |= (u64)(v[rr] != 0u) << (r >> 2);
                }
            }
        }
#pragma unroll
        for (int cc = 0; cc < 4; ++cc)
            mpl[(s * 4 + cc) * 16 + c16] = acc[cc];     // g = s
    }

    // ------------------- Phase A: x pack (linear, L2-hot) ------------------
    {
        const bool xwords = is_word_fmt((const u32*)x);
        const int wv = tid >> 6;                        // wave 0..3
        if (xwords) {
            const uint4* src = (const uint4*)x;         // 65536 uint4
#pragma unroll 8
            for (int k = 0; k < 256; ++k) {
                const int B = wv * 256 + k;             // word-block 0..1023
                const uint4 v = src[(size_t)B * 64 + lane];
                const u64 b0 = __ballot(v.x != 0u);
                const u64 b1 = __ballot(v.y != 0u);
                const u64 b2 = __ballot(v.z != 0u);
                const u64 b3 = __ballot(v.w != 0u);
                if (lane < 4) {
                    const u64 bb = lane == 0 ? b0 : lane == 1 ? b1
                                 : lane == 2 ? b2 : b3;
                    xp[B * 4 + lane] = bb;
                }
            }
        } else {
            const u32* src = (const u32*)x;             // 65536 u32 (4 bools)
#pragma unroll 8
            for (int k = 0; k < 256; ++k) {
                const int B = wv * 256 + k;
                const u32 v = src[(size_t)B * 64 + lane];
                const u64 b0 = __ballot((v & 0x000000FFu) != 0u);
                const u64 b1 = __ballot((v & 0x0000FF00u) != 0u);
                const u64 b2 = __ballot((v & 0x00FF0000u) != 0u);
                const u64 b3 = __ballot((v & 0xFF000000u) != 0u);
                if (lane < 4) {
                    const u64 bb = lane == 0 ? b0 : lane == 1 ? b1
                                 : lane == 2 ? b2 : b3;
                    xp[B * 4 + lane] = bb;
                }
            }
        }
    }

    __syncthreads();

    // ------------------- Phase C: bnn + threshold --------------------------
    {
        const int c16 = tid & 15;
        const int bq  = tid >> 4;                       // 0..15
        const int o   = o0 + c16;
        const int t   = thr[o];

        int a[4] = {0, 0, 0, 0};
#pragma unroll 4
        for (int gc = 0; gc < 64; ++gc) {               // gc = g*4 + cc
            const u64 m = mpl[gc * 16 + c16];
            const int g = gc >> 2, cc = gc & 3;
#pragma unroll
            for (int j = 0; j < 4; ++j) {
                const int b = bq * 4 + j;
                a[j] += __popcll(xp[(b * 16 + g) * 4 + cc] ^ m);
            }
        }
#pragma unroll
        for (int j = 0; j < 4; ++j) {
            const int b = bq * 4 + j;
            out[(size_t)b * DIM_OUT + o] = (DIM_IN - a[j]) > t ? 1 : 0;
        }
    }
}

// ---------------------------------------------------------------------------
extern "C" void kernel_launch(void* const* d_in, const int* in_sizes, int n_in,
                              void* d_out, int out_size, void* d_ws, size_t ws_size,
                              hipStream_t stream) {
    const void* x     = d_in[0];                 // bool [64][4096]
    const void* masks = d_in[1];                 // bool [4096][4096]
    const int*  thr   = (const int*)d_in[2];     // int32 [4096]
    int* out = (int*)d_out;                      // [64][4096] int32 0/1

    fused1_kernel<<<dim3(256), dim3(256), 0, stream>>>(masks, x, thr, out);
}

// Round 13
// 63.353 us; speedup vs baseline: 4.1332x; 1.6796x over previous
//
#include <hip/hip_runtime.h>
#include <stdint.h>

#define DIM_IN  4096
#define DIM_OUT 4096
#define BATCH   64

typedef unsigned long long u64;
typedef uint32_t u32;

// ---------------------------------------------------------------------------
// Input-format detection (first 8 u32 words):
//   int32 0/1 or float 0.0/1.0 -> "word" layout (4B/bool)
//   uint8 0/1                  -> "byte" layout (1B/bool)
// Rounds 3-10: FETCH ~33.4 MB pins word encoding. P(misclassify) ~ 2^-192.
// ---------------------------------------------------------------------------
__device__ __forceinline__ bool is_word_fmt(const u32* __restrict__ p) {
    bool words = true;
#pragma unroll
    for (int i = 0; i < 8; ++i) {
        u32 v = p[i];
        if (v > 1u && v != 0x3F800000u) words = false;
    }
    return words;
}

// ---------------------------------------------------------------------------
// ONE dispatch, 128 blocks x 512 threads. Block owns a 32-column tile
// o0 = bid*32 — exactly ONE 128-B cache line per mask row (word mode), so
// every fetched line is fully consumed (r12's 2x amplification fixed) and
// out writes are one exclusive line per (b, block).
//
// Bit-order convention (identical for x and masks => popc pairing correct,
// verified absmax 0 in r12): bit l of group (g, cc) <-> index i = g*256+4l+cc.
//
// Phase B (masks -> mpl, 16 KB LDS): thread (c = tid&31, s = tid>>5) owns
//   column o0+c, rows s*256..+255. 256 strided u32 loads, 16-deep staged;
//   wave = 2 row-groups x 32 cols = 2 full lines per load inst (coalesced).
//   acc[rr&3] |= (v!=0) << (rr>>2);  mpl[(s*4+cc)*32 + c] (stride 32 u64
//   = 2-way bank aliasing only, free per m136; r12's x16 conflicts fixed).
// Phase A (x -> xp, 32 KB LDS): linear uint4 + 4 ballots (r12 math).
//   x is 1 MB, L2-resident across replays -> ~4 us of L2-hit reads.
// Phase C: thread (c, bq = tid>>5): for 4 b = bq*4+j:
//   a[j] = sum_gc popc(xp[(b*16+(gc>>2))*4+(gc&3)] ^ mpl[gc*32+c]);
//   out[b][o0+c] = (4096 - a[j]) > thr[o0+c].
// ---------------------------------------------------------------------------
__global__ __launch_bounds__(512) void fused_kernel(
        const void* __restrict__ masks, const void* __restrict__ x,
        const int* __restrict__ thr, int* __restrict__ out) {
    __shared__ u64 xp[64 * 64];    // [b*16+g][cc]       (32 KB)
    __shared__ u64 mpl[64 * 32];   // [(g*4+cc)][c]      (16 KB)

    const int tid  = threadIdx.x;
    const int lane = tid & 63;
    const int o0   = blockIdx.x * 32;

    // ------------------- Phase B: mask tile pack (long pole) ---------------
    {
        const bool words = is_word_fmt((const u32*)masks);
        const int c = tid & 31;
        const int s = tid >> 5;                         // 0..15
        u64 acc[4] = {0ull, 0ull, 0ull, 0ull};

        if (words) {
            const u32* base = (const u32*)masks
                            + (size_t)(s * 256) * DIM_OUT + o0 + c;
#pragma unroll
            for (int rb = 0; rb < 16; ++rb) {
                u32 v[16];
#pragma unroll
                for (int rr = 0; rr < 16; ++rr)
                    v[rr] = base[(size_t)(rb * 16 + rr) * DIM_OUT];
#pragma unroll
                for (int rr = 0; rr < 16; ++rr) {
                    const int r = rb * 16 + rr;         // 0..255 compile-time
                    acc[r & 3] |= (u64)(v[rr] != 0u) << (r >> 2);
                }
            }
        } else {
            const uint8_t* base = (const uint8_t*)masks
                                + (size_t)(s * 256) * DIM_OUT + o0 + c;
#pragma unroll
            for (int rb = 0; rb < 16; ++rb) {
                uint8_t v[16];
#pragma unroll
                for (int rr = 0; rr < 16; ++rr)
                    v[rr] = base[(size_t)(rb * 16 + rr) * DIM_OUT];
#pragma unroll
                for (int rr = 0; rr < 16; ++rr) {
                    const int r = rb * 16 + rr;
                    acc[r & 3] |= (u64)(v[rr] != 0u) << (r >> 2);
                }
            }
        }
#pragma unroll
        for (int cc = 0; cc < 4; ++cc)
            mpl[(s * 4 + cc) * 32 + c] = acc[cc];       // g = s
    }

    // ------------------- Phase A: x pack (linear, L2-hot) ------------------
    {
        const bool xwords = is_word_fmt((const u32*)x);
        const int wv = tid >> 6;                        // wave 0..7
        if (xwords) {
            const uint4* src = (const uint4*)x;         // 65536 uint4
#pragma unroll 8
            for (int k = 0; k < 128; ++k) {
                const int B = wv * 128 + k;             // word-block 0..1023
                const uint4 v = src[(size_t)B * 64 + lane];
                const u64 b0 = __ballot(v.x != 0u);
                const u64 b1 = __ballot(v.y != 0u);
                const u64 b2 = __ballot(v.z != 0u);
                const u64 b3 = __ballot(v.w != 0u);
                if (lane < 4) {
                    const u64 bb = lane == 0 ? b0 : lane == 1 ? b1
                                 : lane == 2 ? b2 : b3;
                    xp[B * 4 + lane] = bb;
                }
            }
        } else {
            const u32* src = (const u32*)x;             // 65536 u32 (4 bools)
#pragma unroll 8
            for (int k = 0; k < 128; ++k) {
                const int B = wv * 128 + k;
                const u32 v = src[(size_t)B * 64 + lane];
                const u64 b0 = __ballot((v & 0x000000FFu) != 0u);
                const u64 b1 = __ballot((v & 0x0000FF00u) != 0u);
                const u64 b2 = __ballot((v & 0x00FF0000u) != 0u);
                const u64 b3 = __ballot((v & 0xFF000000u) != 0u);
                if (lane < 4) {
                    const u64 bb = lane == 0 ? b0 : lane == 1 ? b1
                                 : lane == 2 ? b2 : b3;
                    xp[B * 4 + lane] = bb;
                }
            }
        }
    }

    __syncthreads();

    // ------------------- Phase C: bnn + threshold --------------------------
    {
        const int c  = tid & 31;
        const int bq = tid >> 5;                        // 0..15
        const int o  = o0 + c;
        const int t  = thr[o];

        int a[4] = {0, 0, 0, 0};
#pragma unroll 4
        for (int gc = 0; gc < 64; ++gc) {               // gc = g*4 + cc
            const u64 m = mpl[gc * 32 + c];
            const int g = gc >> 2, cc = gc & 3;
#pragma unroll
            for (int j = 0; j < 4; ++j) {
                const int b = bq * 4 + j;
                a[j] += __popcll(xp[(b * 16 + g) * 4 + cc] ^ m);
            }
        }
#pragma unroll
        for (int j = 0; j < 4; ++j) {
            const int b = bq * 4 + j;
            out[(size_t)b * DIM_OUT + o] = (DIM_IN - a[j]) > t ? 1 : 0;
        }
    }
}

// ---------------------------------------------------------------------------
extern "C" void kernel_launch(void* const* d_in, const int* in_sizes, int n_in,
                              void* d_out, int out_size, void* d_ws, size_t ws_size,
                              hipStream_t stream) {
    const void* x     = d_in[0];                 // bool [64][4096]
    const void* masks = d_in[1];                 // bool [4096][4096]
    const int*  thr   = (const int*)d_in[2];     // int32 [4096]
    int* out = (int*)d_out;                      // [64][4096] int32 0/1

    fused_kernel<<<dim3(128), dim3(512), 0, stream>>>(masks, x, thr, out);
}

// Round 14
// 57.697 us; speedup vs baseline: 4.5384x; 1.0980x over previous
//
#include <hip/hip_runtime.h>
#include <stdint.h>

#define DIM_IN  4096
#define DIM_OUT 4096
#define BATCH   64

typedef unsigned long long u64;
typedef uint32_t u32;

#define NBLK1 2048           // compress blocks
#define NTHR  (NBLK1 * 256)  // 524288 threads; x8 units/thread = full array

// ---------------------------------------------------------------------------
// Input-format detection (first 8 u32 words):
//   int32 0/1 or float 0.0/1.0 -> "word" layout (4B/bool)
//   uint8 0/1                  -> "byte" layout (1B/bool)
// Rounds 3-10: FETCH ~33.4 MB pins word encoding. P(misclassify) ~ 2^-192.
// ---------------------------------------------------------------------------
__device__ __forceinline__ bool is_word_fmt(const u32* __restrict__ p) {
    bool words = true;
#pragma unroll
    for (int i = 0; i < 8; ++i) {
        u32 v = p[i];
        if (v > 1u && v != 0x3F800000u) words = false;
    }
    return words;
}

// ---------------------------------------------------------------------------
// K1: linear compress (r10's verified kernel — the only structure that beat
// the ~0.8 TB/s strided wall; it profiled BELOW the 38.7 µs fills) + x-pack.
//
// Element mapping (both modes): unit u holds elements 4u..4u+3; ballot over
// lanes l of component c -> rp[(u>>6)*4 + c] bit l, u = chunk*64 + l.
// So element m = i*4096+o: rp[(m>>8)*4 + (m&3)] bit ((m>>2)&63).
// blocks 2048..2063: x pack -> xp[b*64+w] bit l = x[b][w*64+l] (canonical).
// ---------------------------------------------------------------------------
__global__ __launch_bounds__(256) void compress_kernel(
        const void* __restrict__ masks, const void* __restrict__ x,
        u64* __restrict__ rp, u64* __restrict__ xp) {
    const int bid  = blockIdx.x;
    const int tid  = threadIdx.x;
    const int lane = tid & 63;

    if (bid < NBLK1) {
        const bool words = is_word_fmt((const u32*)masks);
        const int T = bid * 256 + tid;
        if (words) {
            const uint4* src = (const uint4*)masks;        // 4M uint4
            uint4 v[8];
#pragma unroll
            for (int it = 0; it < 8; ++it)
                v[it] = src[(size_t)T + (size_t)it * NTHR];
#pragma unroll
            for (int it = 0; it < 8; ++it) {
                const u64 b0 = __ballot(v[it].x != 0u);
                const u64 b1 = __ballot(v[it].y != 0u);
                const u64 b2 = __ballot(v[it].z != 0u);
                const u64 b3 = __ballot(v[it].w != 0u);
                const size_t chunk = ((size_t)T + (size_t)it * NTHR) >> 6;
                if (lane < 4) {
                    const u64 bb = lane == 0 ? b0 : lane == 1 ? b1
                                 : lane == 2 ? b2 : b3;
                    rp[chunk * 4 + lane] = bb;
                }
            }
        } else {
            const u32* src = (const u32*)masks;            // 4.19M u32
            u32 v[8];
#pragma unroll
            for (int it = 0; it < 8; ++it)
                v[it] = src[(size_t)T + (size_t)it * NTHR];
#pragma unroll
            for (int it = 0; it < 8; ++it) {
                const u64 b0 = __ballot((v[it] & 0x000000FFu) != 0u);
                const u64 b1 = __ballot((v[it] & 0x0000FF00u) != 0u);
                const u64 b2 = __ballot((v[it] & 0x00FF0000u) != 0u);
                const u64 b3 = __ballot((v[it] & 0xFF000000u) != 0u);
                const size_t chunk = ((size_t)T + (size_t)it * NTHR) >> 6;
                if (lane < 4) {
                    const u64 bb = lane == 0 ? b0 : lane == 1 ? b1
                                 : lane == 2 ? b2 : b3;
                    rp[chunk * 4 + lane] = bb;
                }
            }
        }
    } else {
        // ------------------- x pack (16 blocks, 64 waves) -------------------
        const bool xwords = is_word_fmt((const u32*)x);
        const int bxid = bid - NBLK1;                         // 0..15
        const int wave = bxid * 4 + (tid >> 6);               // 0..63
        const int base = wave * 64;                           // = b*64 range
#pragma unroll 16
        for (int k = 0; k < 64; ++k) {
            const int idx = base + k;                         // b*64 + w
            const size_t e = (size_t)idx * 64 + lane;
            bool pred;
            if (xwords) pred = ((const u32*)x)[e] != 0u;
            else        pred = ((const uint8_t*)x)[e] != 0u;
            const u64 m = __ballot(pred);
            if (lane == 0) xp[idx] = m;
        }
    }
}

// ---------------------------------------------------------------------------
// K2: fused transpose+bnn, 256 blocks x 512 threads (1+ block/CU).
// Block: oseg = bid&63 (cols o0=oseg*64), bq = bid>>6 (16 batch rows).
//
// T-phase (r10's verified ballot transpose, LDS dest): wave wv, rep 0..7,
//   tile w = wv*8+rep; lane r holds row (w*64+r)'s 4 rp words at jbase;
//   64 ballots extract bit (Lbase+(d>>2)) of word (d&3) -> column word d;
//   lane d keeps it; mpT[w*64+r(=d)] bit r' = masks[w*64+r'][o0+d]. 32 KB.
// bnn: thread (c=tid&63, bslot=tid>>6): 2 b's; a += popc(xpL[bl*64+w] ^
//   mpT[w*64+c]); out[b][o0+c] = (4096-a) > thr. xpL wave-uniform reads
//   (broadcast), mpT consecutive (2-way aliasing, free).
// ---------------------------------------------------------------------------
__global__ __launch_bounds__(512) void tb_kernel(
        const u64* __restrict__ rp, const u64* __restrict__ xp,
        const int* __restrict__ thr, int* __restrict__ out) {
    __shared__ u64 mpT[64 * 64];   // 32 KB
    __shared__ u64 xpL[16 * 64];   // 8 KB

    const int tid  = threadIdx.x;
    const int oseg = blockIdx.x & 63;
    const int bq   = blockIdx.x >> 6;                    // 0..3
    const int o0   = oseg * 64;
    const int r    = tid & 63;
    const int wv   = tid >> 6;                           // 0..7

    // stage this block's 16 batch rows of xp (1024 u64 = 8 KB)
#pragma unroll
    for (int k = tid; k < 1024; k += 512)
        xpL[k] = xp[(size_t)bq * 1024 + k];

    const int jbase = (o0 >> 8) * 4;
    const int Lbase = (o0 & 255) >> 2;                   // 0,16,32,48

#pragma unroll
    for (int rep = 0; rep < 8; ++rep) {
        const int w = wv * 8 + rep;                      // 0..63
        const u64* rowp = rp + (size_t)(w * 64 + r) * 64 + jbase;
        const u64 rw0 = rowp[0];
        const u64 rw1 = rowp[1];
        const u64 rw2 = rowp[2];
        const u64 rw3 = rowp[3];

        u64 mine = 0;
#pragma unroll
        for (int d = 0; d < 64; ++d) {
            const u64 srcw = (d & 3) == 0 ? rw0 : (d & 3) == 1 ? rw1
                           : (d & 3) == 2 ? rw2 : rw3;
            const int sh = Lbase + (d >> 2);
            const u64 m = __ballot(((srcw >> sh) & 1ull) != 0ull);
            if (r == d) mine = m;
        }
        mpT[w * 64 + r] = mine;
    }

    __syncthreads();

    // ------------------------------ bnn ------------------------------------
    {
        const int c     = tid & 63;
        const int bslot = tid >> 6;                      // 0..7
        const int o     = o0 + c;
        const int t     = thr[o];
        const int bl0   = bslot * 2;

        int a0 = 0, a1 = 0;
#pragma unroll 16
        for (int w = 0; w < 64; ++w) {
            const u64 m = mpT[w * 64 + c];
            a0 += __popcll(xpL[(bl0 + 0) * 64 + w] ^ m);
            a1 += __popcll(xpL[(bl0 + 1) * 64 + w] ^ m);
        }

        const int b = bq * 16 + bl0;
        out[(size_t)(b + 0) * DIM_OUT + o] = (DIM_IN - a0) > t ? 1 : 0;
        out[(size_t)(b + 1) * DIM_OUT + o] = (DIM_IN - a1) > t ? 1 : 0;
    }
}

// ---------------------------------------------------------------------------
extern "C" void kernel_launch(void* const* d_in, const int* in_sizes, int n_in,
                              void* d_out, int out_size, void* d_ws, size_t ws_size,
                              hipStream_t stream) {
    const void* x     = d_in[0];                 // bool [64][4096]
    const void* masks = d_in[1];                 // bool [4096][4096]
    const int*  thr   = (const int*)d_in[2];     // int32 [4096]
    int* out = (int*)d_out;                      // [64][4096] int32 0/1

    u64* rp = (u64*)d_ws;                                        // 2 MiB
    u64* xp = (u64*)((char*)d_ws + (size_t)2 * 1024 * 1024);     // 32 KiB

    compress_kernel<<<dim3(NBLK1 + 16), dim3(256), 0, stream>>>(masks, x, rp, xp);
    tb_kernel<<<dim3(256), dim3(512), 0, stream>>>(rp, xp, thr, out);
}

// Round 15
// 42.898 us; speedup vs baseline: 6.1040x; 1.3450x over previous
//
#include <hip/hip_runtime.h>
#include <stdint.h>

#define DIM_IN  4096
#define DIM_OUT 4096
#define BATCH   64

typedef unsigned long long u64;
typedef uint32_t u32;

// ---------------------------------------------------------------------------
// Input-format detection (first 8 u32 words):
//   int32 0/1 or float 0.0/1.0 -> "word" layout (4B/bool)
//   uint8 0/1                  -> "byte" layout (1B/bool)
// Encoding is now PROVEN word-mode by cache arithmetic: FETCH is always
// ~67-32=35 MB; a 16.7 MB byte array would fit L2 entirely (FETCH -> ~0).
// Byte path kept purely as a safety net.
// ---------------------------------------------------------------------------
__device__ __forceinline__ bool is_word_fmt(const u32* __restrict__ p) {
    bool words = true;
#pragma unroll
    for (int i = 0; i < 8; ++i) {
        u32 v = p[i];
        if (v > 1u && v != 0x3F800000u) words = false;
    }
    return words;
}

// Direct global->LDS DMA, 16 B per lane. Global address is PER-LANE; LDS
// destination is wave-uniform base + lane*16 (HW rule). The compiler cannot
// serialize these through VGPR dependencies — true MLP, counted by vmcnt.
__device__ __forceinline__ void gl_lds16(const u32* g, u32* l) {
    __builtin_amdgcn_global_load_lds(
        (const __attribute__((address_space(1))) u32*)g,
        (__attribute__((address_space(3))) u32*)l, 16, 0, 0);
}

// ---------------------------------------------------------------------------
// K1 pack, 1040 blocks x 256 threads, 64 KB LDS.
//
// blocks 0..1023: mask pack. Block = (w = bid>>4, oseg = bid&15).
//   Columns o0 = oseg*256 .. +255; rows row0 = w*64 .. +63.
//   DMA phase: wave wv stages rows wv*16..+15: one global_load_lds dwordx4
//   per row (lane provides gbase + r*4096 + lane*4; 64 lanes x 16 B = 1 KB =
//   the row's 256 columns) -> tile[r*256 + lane*4]. 16 loads in flight per
//   wave, no VGPR round-trip. s_waitcnt vmcnt(0) + __syncthreads.
//   Consume: thread t = column c: bits |= (tile[r*256+c]!=0) << r, r=0..63;
//   LDS reads are lane-consecutive (2-way bank aliasing = free).
//   Store: mp[w*4096 + o0 + c] — canonical layout, coalesced 2 KB/block.
//
// blocks 1024..1039: x pack via wave ballot (canonical xp, verified r8/r14).
// ---------------------------------------------------------------------------
__global__ __launch_bounds__(256) void pack_kernel(
        const void* __restrict__ masks, const void* __restrict__ x,
        u64* __restrict__ mp, u64* __restrict__ xp) {
    __shared__ u32 tile[64 * 256];   // 64 KB
    const int bid  = blockIdx.x;
    const int tid  = threadIdx.x;
    const int lane = tid & 63;

    if (bid < 1024) {
        const bool words = is_word_fmt((const u32*)masks);
        const int w    = bid >> 4;                       // 0..63
        const int oseg = bid & 15;                       // 0..15
        const int o0   = oseg * 256;
        const int row0 = w * 64;

        if (words) {
            const int wv = tid >> 6;                     // 0..3
            const u32* gbase = (const u32*)masks
                             + (size_t)row0 * DIM_OUT + o0 + lane * 4;
#pragma unroll
            for (int k = 0; k < 16; ++k) {
                const int r = wv * 16 + k;
                gl_lds16(gbase + (size_t)r * DIM_OUT, &tile[r * 256]);
            }
            asm volatile("s_waitcnt vmcnt(0)" ::: "memory");
            __syncthreads();

            u32 lo = 0, hi = 0;
#pragma unroll
            for (int r = 0; r < 32; ++r)
                lo |= (u32)(tile[r * 256 + tid] != 0u) << r;
#pragma unroll
            for (int r = 32; r < 64; ++r)
                hi |= (u32)(tile[r * 256 + tid] != 0u) << (r - 32);
            mp[(size_t)w * DIM_OUT + o0 + tid] = (u64)lo | ((u64)hi << 32);
        } else {
            // byte-mode safety net (plain strided loads, r8-style)
            const uint8_t* base = (const uint8_t*)masks
                                + (size_t)row0 * DIM_OUT + o0 + tid;
            u32 lo = 0, hi = 0;
#pragma unroll
            for (int r = 0; r < 32; ++r)
                lo |= (u32)(base[(size_t)r * DIM_OUT] != 0u) << r;
#pragma unroll
            for (int r = 32; r < 64; ++r)
                hi |= (u32)(base[(size_t)r * DIM_OUT] != 0u) << (r - 32);
            mp[(size_t)w * DIM_OUT + o0 + tid] = (u64)lo | ((u64)hi << 32);
        }
    } else {
        // ------------------- x pack (16 blocks, 64 waves) -------------------
        const bool xwords = is_word_fmt((const u32*)x);
        const int bxid = bid - 1024;                         // 0..15
        const int wave = bxid * 4 + (tid >> 6);              // 0..63
        const int base = wave * 64;                          // b*64 + w range
#pragma unroll 16
        for (int k = 0; k < 64; ++k) {
            const int idx = base + k;                        // b*64 + w
            const size_t e = (size_t)idx * 64 + lane;        // x[b][w*64+lane]
            bool pred;
            if (xwords) pred = ((const u32*)x)[e] != 0u;
            else        pred = ((const uint8_t*)x)[e] != 0u;
            const u64 m = __ballot(pred);
            if (lane == 0) xp[idx] = m;
        }
    }
}

// ---------------------------------------------------------------------------
// K2: out[b][o] = ((4096 - sum_w popc(xp[b][w] ^ mp[w][o])) > thr[o]) ? 1 : 0
// Output dtype INT32 (bool output -> int32 harness path). Verified absmax 0
// in rounds 2-9. Grid: (16 o-blocks, 16 b-blocks) x 256 threads.
// ---------------------------------------------------------------------------
__global__ __launch_bounds__(256) void bnn_kernel(
        const u64* __restrict__ mp, const u64* __restrict__ xp,
        const int* __restrict__ thr, int* __restrict__ out) {
    const int o  = blockIdx.x * 256 + threadIdx.x;
    const int b0 = blockIdx.y * 4;

    const u64* __restrict__ x0 = xp + (size_t)(b0 + 0) * 64;
    const u64* __restrict__ x1 = xp + (size_t)(b0 + 1) * 64;
    const u64* __restrict__ x2 = xp + (size_t)(b0 + 2) * 64;
    const u64* __restrict__ x3 = xp + (size_t)(b0 + 3) * 64;

    int a0 = 0, a1 = 0, a2 = 0, a3 = 0;
#pragma unroll 16
    for (int w = 0; w < 64; ++w) {
        const u64 mw = mp[(size_t)w * DIM_OUT + o];
        a0 += __popcll(x0[w] ^ mw);
        a1 += __popcll(x1[w] ^ mw);
        a2 += __popcll(x2[w] ^ mw);
        a3 += __popcll(x3[w] ^ mw);
    }

    const int t = thr[o];
    out[(size_t)(b0 + 0) * DIM_OUT + o] = (DIM_IN - a0) > t ? 1 : 0;
    out[(size_t)(b0 + 1) * DIM_OUT + o] = (DIM_IN - a1) > t ? 1 : 0;
    out[(size_t)(b0 + 2) * DIM_OUT + o] = (DIM_IN - a2) > t ? 1 : 0;
    out[(size_t)(b0 + 3) * DIM_OUT + o] = (DIM_IN - a3) > t ? 1 : 0;
}

// ---------------------------------------------------------------------------
extern "C" void kernel_launch(void* const* d_in, const int* in_sizes, int n_in,
                              void* d_out, int out_size, void* d_ws, size_t ws_size,
                              hipStream_t stream) {
    const void* x     = d_in[0];                 // bool [64][4096]
    const void* masks = d_in[1];                 // bool [4096][4096]
    const int*  thr   = (const int*)d_in[2];     // int32 [4096]
    int* out = (int*)d_out;                      // [64][4096] int32 0/1

    u64* mp = (u64*)d_ws;                                        // 2 MiB
    u64* xp = (u64*)((char*)d_ws + (size_t)2 * 1024 * 1024);     // 32 KiB

    pack_kernel<<<dim3(1040), dim3(256), 0, stream>>>(masks, x, mp, xp);
    bnn_kernel<<<dim3(16, 16), dim3(256), 0, stream>>>(mp, xp, thr, out);
}

// Round 16
// 38.086 us; speedup vs baseline: 6.8752x; 1.1263x over previous
//
#include <hip/hip_runtime.h>
#include <stdint.h>

#define DIM_IN  4096
#define DIM_OUT 4096
#define BATCH   64
// words along dim_in: 4096/64 = 64

typedef unsigned long long u64;
typedef uint32_t u32;

// ---------------------------------------------------------------------------
// FINAL (restored round-8 kernel — best measured: 38.05 us bench total).
//
// Structural model (rounds 3-15): masks = 67 MB int32-encoded bools, re-read
// every call. Compulsory L2-miss volume = 67 - 32 (L2) ~= 33.4 MB (observed
// FETCH byte-identical across ALL 13 pack variants). The miss stream is
// served at a fixed ~0.75 TB/s regardless of pattern/width/MLP/occupancy/
// NT/DMA => pack ~= 33 us replay-mode. bnn ~3 us + ~2-4 us dispatch overhead
// => ~38 us total. This is the HIP-reachable floor for this op on this chip.
// ---------------------------------------------------------------------------
__device__ __forceinline__ bool is_word_fmt(const u32* __restrict__ p) {
    bool words = true;
#pragma unroll
    for (int i = 0; i < 8; ++i) {
        u32 v = p[i];
        if (v > 1u && v != 0x3F800000u) words = false;
    }
    return words;
}

// ---------------------------------------------------------------------------
// K1 (fused pack), 272 blocks x 256 threads.
//
// blocks 0..255: mask pack, wide loads (16 B/lane).
//   Block b: w = b>>2 (row-group), oseg = b&3 (1024-col segment).
//   Thread t owns 4 adjacent columns o = oseg*1024 + t*4.
//   Per row the block reads a contiguous 4 KB chunk (256 thr x uint4);
//   64 rows in 8 batches of 8 staged uint4 loads.
//   Bit-slices accumulate in registers (no transpose); stores are 4
//   contiguous u64 per thread (32 B), 8 KB exclusive per block.
//
// blocks 256..271: x pack via wave ballot (64 waves x 64 words).
// ---------------------------------------------------------------------------
__global__ __launch_bounds__(256) void pack_kernel(
        const void* __restrict__ masks, const void* __restrict__ x,
        u64* __restrict__ mp, u64* __restrict__ xp) {
    const int bid = blockIdx.x;
    if (bid < 256) {
        const bool words = is_word_fmt((const u32*)masks);
        const int w    = bid >> 2;                        // 0..63
        const int oseg = bid & 3;                         // 0..3
        const int o0   = oseg * 1024 + threadIdx.x * 4;   // 4 adjacent columns
        const int row0 = w * 64;

        u32 lo[4] = {0u, 0u, 0u, 0u};
        u32 hi[4] = {0u, 0u, 0u, 0u};

        if (words) {
            const u32* base = (const u32*)masks + (size_t)row0 * DIM_OUT + o0;
#pragma unroll
            for (int rb = 0; rb < 8; ++rb) {
                uint4 v[8];
#pragma unroll
                for (int r = 0; r < 8; ++r)
                    v[r] = *reinterpret_cast<const uint4*>(
                               base + (size_t)(rb * 8 + r) * DIM_OUT);
#pragma unroll
                for (int r = 0; r < 8; ++r) {
                    const int row = rb * 8 + r;           // compile-time
                    if (row < 32) {
                        lo[0] |= (u32)(v[r].x != 0u) << row;
                        lo[1] |= (u32)(v[r].y != 0u) << row;
                        lo[2] |= (u32)(v[r].z != 0u) << row;
                        lo[3] |= (u32)(v[r].w != 0u) << row;
                    } else {
                        hi[0] |= (u32)(v[r].x != 0u) << (row - 32);
                        hi[1] |= (u32)(v[r].y != 0u) << (row - 32);
                        hi[2] |= (u32)(v[r].z != 0u) << (row - 32);
                        hi[3] |= (u32)(v[r].w != 0u) << (row - 32);
                    }
                }
            }
        } else {
            // byte layout: thread's 4 columns = one u32 per row.
            const u32* base = (const u32*)((const uint8_t*)masks
                                + (size_t)row0 * DIM_OUT + o0);
#pragma unroll
            for (int rb = 0; rb < 8; ++rb) {
                u32 v[8];
#pragma unroll
                for (int r = 0; r < 8; ++r)
                    v[r] = base[(size_t)(rb * 8 + r) * (DIM_OUT / 4)];
#pragma unroll
                for (int r = 0; r < 8; ++r) {
                    const int row = rb * 8 + r;
                    if (row < 32) {
                        lo[0] |= (u32)((v[r] & 0x000000FFu) != 0u) << row;
                        lo[1] |= (u32)((v[r] & 0x0000FF00u) != 0u) << row;
                        lo[2] |= (u32)((v[r] & 0x00FF0000u) != 0u) << row;
                        lo[3] |= (u32)((v[r] & 0xFF000000u) != 0u) << row;
                    } else {
                        hi[0] |= (u32)((v[r] & 0x000000FFu) != 0u) << (row - 32);
                        hi[1] |= (u32)((v[r] & 0x0000FF00u) != 0u) << (row - 32);
                        hi[2] |= (u32)((v[r] & 0x00FF0000u) != 0u) << (row - 32);
                        hi[3] |= (u32)((v[r] & 0xFF000000u) != 0u) << (row - 32);
                    }
                }
            }
        }

        u64* dst = mp + (size_t)w * DIM_OUT + o0;
#pragma unroll
        for (int c = 0; c < 4; ++c)
            dst[c] = (u64)lo[c] | ((u64)hi[c] << 32);
    } else {
        // ------------------- x pack -------------------
        const bool words = is_word_fmt((const u32*)x);
        const int bxid = bid - 256;                           // 0..15
        const int wave = bxid * 4 + (threadIdx.x >> 6);       // 0..63
        const int lane = threadIdx.x & 63;
        const int base = wave * 64;                           // word index base

#pragma unroll 16
        for (int k = 0; k < 64; ++k) {
            const int idx = base + k;                         // 0..4095
            const size_t e = (size_t)idx * 64 + lane;         // element index
            bool pred;
            if (words) pred = ((const u32*)x)[e] != 0u;
            else       pred = ((const uint8_t*)x)[e] != 0u;
            const u64 m = __ballot(pred);
            if (lane == 0) xp[idx] = m;
        }
    }
}

// ---------------------------------------------------------------------------
// K2: out[b][o] = ((4096 - sum_w popc(xp[b][w] ^ mp[w][o])) > thr[o]) ? 1 : 0
// Output dtype INT32 (bool output -> int32 harness path).
// Grid: (16 o-blocks, 16 b-blocks) x 256 threads; 4 batch rows per thread.
// ---------------------------------------------------------------------------
__global__ __launch_bounds__(256) void bnn_kernel(
        const u64* __restrict__ mp, const u64* __restrict__ xp,
        const int* __restrict__ thr, int* __restrict__ out) {
    const int o  = blockIdx.x * 256 + threadIdx.x;
    const int b0 = blockIdx.y * 4;

    const u64* __restrict__ x0 = xp + (size_t)(b0 + 0) * 64;
    const u64* __restrict__ x1 = xp + (size_t)(b0 + 1) * 64;
    const u64* __restrict__ x2 = xp + (size_t)(b0 + 2) * 64;
    const u64* __restrict__ x3 = xp + (size_t)(b0 + 3) * 64;

    int a0 = 0, a1 = 0, a2 = 0, a3 = 0;
#pragma unroll 16
    for (int w = 0; w < 64; ++w) {
        const u64 mw = mp[(size_t)w * DIM_OUT + o];
        a0 += __popcll(x0[w] ^ mw);
        a1 += __popcll(x1[w] ^ mw);
        a2 += __popcll(x2[w] ^ mw);
        a3 += __popcll(x3[w] ^ mw);
    }

    const int t = thr[o];
    out[(size_t)(b0 + 0) * DIM_OUT + o] = (DIM_IN - a0) > t ? 1 : 0;
    out[(size_t)(b0 + 1) * DIM_OUT + o] = (DIM_IN - a1) > t ? 1 : 0;
    out[(size_t)(b0 + 2) * DIM_OUT + o] = (DIM_IN - a2) > t ? 1 : 0;
    out[(size_t)(b0 + 3) * DIM_OUT + o] = (DIM_IN - a3) > t ? 1 : 0;
}

// ---------------------------------------------------------------------------
extern "C" void kernel_launch(void* const* d_in, const int* in_sizes, int n_in,
                              void* d_out, int out_size, void* d_ws, size_t ws_size,
                              hipStream_t stream) {
    const void* x     = d_in[0];                 // bool [64][4096]
    const void* masks = d_in[1];                 // bool [4096][4096]
    const int*  thr   = (const int*)d_in[2];     // int32 [4096]
    int* out = (int*)d_out;                      // [64][4096] int32 0/1

    u64* mp = (u64*)d_ws;                                        // 2 MiB
    u64* xp = (u64*)((char*)d_ws + (size_t)64 * DIM_OUT * 8);    // 32 KiB

    pack_kernel<<<dim3(272), dim3(256), 0, stream>>>(masks, x, mp, xp);
    bnn_kernel<<<dim3(16, 16), dim3(256), 0, stream>>>(mp, xp, thr, out);
}